// Round 3
// baseline (861.595 us; speedup 1.0000x reference)
//
#include <hip/hip_runtime.h>
#include <hip/hip_bf16.h>

// SoftAttention fused pipeline for MI355X (gfx950).
// R3: feature pre-converted to bf16 (cvtA_k) so score_gemm_k stages BOTH
// operands via global_load_lds dwordx4 (zero staging VALU — m97 structure),
// W_enc pre-transposed to bf16 [a][d] (prepBT_k), wsum reads bf16 copy.
// Fallback to R2 path (fp32 VGPR staging) if ws_size too small for the
// 196 MB bf16 feature scratch.

typedef unsigned short u16;
typedef __attribute__((ext_vector_type(8))) short short8;       // 8 bf16
typedef __attribute__((ext_vector_type(8))) unsigned short u16x8;
typedef __attribute__((ext_vector_type(4))) float f32x4;

#define BATCH 256
#define LQ    196
#define DDIM  2048
#define ADIM  512
#define MTOT  (BATCH * LQ)   /* 50176 = 392*128 */
#define WF_N  (BATCH * DDIM)
#define KQP   1032           /* slow-path padded plane stride */

__device__ __forceinline__ u16 f2bf(float f) {
  unsigned u = __builtin_bit_cast(unsigned, f);
  return (u16)((u + 0x7FFFu + ((u >> 16) & 1u)) >> 16);
}
__device__ __forceinline__ float bf2f(u16 x) {
  return __builtin_bit_cast(float, (unsigned)x << 16);
}
__device__ __forceinline__ ushort4 cvt4(float4 f) {
  ushort4 r;
  r.x = f2bf(f.x); r.y = f2bf(f.y); r.z = f2bf(f.z); r.w = f2bf(f.w);
  return r;
}
__device__ __forceinline__ void glds16(const u16* g, u16* l) {
  __builtin_amdgcn_global_load_lds(
      (const __attribute__((address_space(1))) unsigned int*)g,
      (__attribute__((address_space(3))) unsigned int*)l, 16, 0, 0);
}

// ---------------- cvtA: feature fp32 -> bf16, plain row-major
// grid 12544 x 256, 4 units of 8 floats per thread == 102,760,448 exactly
__global__ void cvtA_k(const float* __restrict__ f, u16* __restrict__ o) {
  size_t i = (size_t)blockIdx.x * 256 + threadIdx.x;
  const size_t stride = (size_t)12544 * 256;
  #pragma unroll
  for (int k = 0; k < 4; k++, i += stride) {
    const float4* p = (const float4*)(f + i * 8);
    float4 x = p[0], y = p[1];
    ushort4 a = cvt4(x), b = cvt4(y);
    u16x8 v = {a.x, a.y, a.z, a.w, b.x, b.y, b.z, b.w};
    *(u16x8*)(o + i * 8) = v;
  }
}

// ---------------- prepBT: W_enc (2048,512) fp32 -> WencT (512,2048) bf16
__global__ void prepBT_k(const float* __restrict__ W_enc, u16* __restrict__ WencT) {
  const int dt = blockIdx.x >> 3;   // 0..31
  const int at = blockIdx.x & 7;    // 0..7
  const int tid = threadIdx.x;
  __shared__ u16 t[64][72];         // [d_local][a_local], padded
  const int r = tid >> 2, c4 = tid & 3;
  #pragma unroll
  for (int k = 0; k < 4; k++) {
    int c = (c4 + k * 4) * 4;       // a_local col
    float4 v = *(const float4*)(W_enc + (size_t)(dt * 64 + r) * 512 + at * 64 + c);
    *(ushort4*)&t[r][c] = cvt4(v);
  }
  __syncthreads();
  #pragma unroll
  for (int k = 0; k < 4; k++) {
    int d = c4 * 16 + k * 4;
    ushort4 v = {t[d][r], t[d + 1][r], t[d + 2][r], t[d + 3][r]};
    *(ushort4*)(WencT + (size_t)(at * 64 + r) * 2048 + dt * 64 + d) = v;
  }
}

// ---------------- att2[n][a] = b_dec[a] + b_enc[a] + prev_h[n]@W_dec[:,a]
__global__ void att2_k(const float* __restrict__ prev_h,
                       const float* __restrict__ W_dec,
                       const float* __restrict__ b_dec,
                       const float* __restrict__ b_enc,
                       float* __restrict__ att2) {
  const int n = blockIdx.x, tid = threadIdx.x;
  __shared__ float ph[512];
  ph[tid]       = prev_h[n * 512 + tid];
  ph[tid + 256] = prev_h[n * 512 + tid + 256];
  __syncthreads();
  float a0 = b_dec[tid] + b_enc[tid];
  float a1 = b_dec[tid + 256] + b_enc[tid + 256];
  #pragma unroll 8
  for (int h = 0; h < 512; h++) {
    float p = ph[h];
    a0 = fmaf(p, W_dec[h * 512 + tid], a0);
    a1 = fmaf(p, W_dec[h * 512 + tid + 256], a1);
  }
  att2[n * 512 + tid] = a0;
  att2[n * 512 + tid + 256] = a1;
}

__global__ void zero_scores_k(float* __restrict__ s) {
  s[blockIdx.x * 256 + threadIdx.x] = 0.f;
}

// ---------------- fast GEMM: both operands via global_load_lds, dbuf
// grid 1568; block 256 = 4 waves (2x2); XCD swizzle as R2
__global__ __launch_bounds__(256, 4) void score_gemm_k(
    const u16* __restrict__ featB, const u16* __restrict__ WencT,
    const float* __restrict__ att2, const float* __restrict__ W_tot,
    float* __restrict__ scores) {
  __shared__ __align__(16) u16 sA[2][4096];   // [buf][kq][row=128][8]
  __shared__ __align__(16) u16 sB[2][4096];
  __shared__ float sRed[2][128];

  const int tid = threadIdx.x;
  const int b = blockIdx.x;
  const int mt = (b >> 5) * 8 + (b & 7);   // b%8 = XCD; nt siblings 8 apart
  const int nt = (b >> 3) & 3;
  const int r0 = mt << 7, n0 = nt << 7;
  const int wid = tid >> 6, lane = tid & 63;
  const int wgm = wid >> 1, wgn = wid & 1;
  const int quad = lane >> 4, cid = lane & 15;

  // wave `wid` stages kq-plane `wid`; lane -> row (2 instrs: rows 0-63,64-127)
  const u16* gA0 = featB + (size_t)(r0 + lane) * 2048 + wid * 8;
  const u16* gB0 = WencT + (size_t)(n0 + lane) * 2048 + wid * 8;

  const int abase = (quad << 10) + (((wgm << 6) + cid) << 3);
  const int bbase = (quad << 10) + (((wgn << 6) + cid) << 3);

  f32x4 zero = {0.f, 0.f, 0.f, 0.f};
  f32x4 acc[4][4];
  #pragma unroll
  for (int i = 0; i < 4; i++)
    #pragma unroll
    for (int j = 0; j < 4; j++) acc[i][j] = zero;

  // prologue: tile ks=0 -> buf 0
  {
    u16* dA = &sA[0][wid << 10];
    u16* dB = &sB[0][wid << 10];
    glds16(gA0, dA);
    glds16(gA0 + 64 * 2048, dA + 512);
    glds16(gB0, dB);
    glds16(gB0 + 64 * 2048, dB + 512);
  }

  #pragma unroll 2
  for (int ks = 0; ks < 64; ks++) {
    const int buf = ks & 1;
    __syncthreads();               // drains glds for tile ks
    if (ks < 63) {                 // prefetch ks+1 over this tile's compute
      const int o = (ks + 1) << 5;
      u16* dA = &sA[buf ^ 1][wid << 10];
      u16* dB = &sB[buf ^ 1][wid << 10];
      glds16(gA0 + o, dA);
      glds16(gA0 + o + 64 * 2048, dA + 512);
      glds16(gB0 + o, dB);
      glds16(gB0 + o + 64 * 2048, dB + 512);
    }
    const u16* sa = &sA[buf][abase];
    const u16* sb = &sB[buf][bbase];
    short8 af[4], bfr[4];
    #pragma unroll
    for (int mi = 0; mi < 4; mi++)
      af[mi] = *(const short8*)(sa + (mi << 7));
    #pragma unroll
    for (int ni = 0; ni < 4; ni++)
      bfr[ni] = *(const short8*)(sb + (ni << 7));
    #pragma unroll
    for (int mi = 0; mi < 4; mi++)
      #pragma unroll
      for (int ni = 0; ni < 4; ni++)
        acc[mi][ni] = __builtin_amdgcn_mfma_f32_16x16x32_bf16(
            af[mi], bfr[ni], acc[mi][ni], 0, 0, 0);
  }

  float wt[4];
  #pragma unroll
  for (int ni = 0; ni < 4; ni++)
    wt[ni] = W_tot[n0 + (wgn << 6) + ni * 16 + cid];

  #pragma unroll
  for (int mi = 0; mi < 4; mi++) {
    #pragma unroll
    for (int reg = 0; reg < 4; reg++) {
      int row_local = (wgm << 6) + mi * 16 + quad * 4 + reg;
      int row_flat = r0 + row_local;
      int nb = row_flat / 196;
      const float* a2r = att2 + nb * 512 + n0 + (wgn << 6);
      float s = 0.f;
      #pragma unroll
      for (int ni = 0; ni < 4; ni++) {
        float v = acc[mi][ni][reg] + a2r[ni * 16 + cid];
        s += fmaxf(v, 0.f) * wt[ni];
      }
      s += __shfl_xor(s, 1); s += __shfl_xor(s, 2);
      s += __shfl_xor(s, 4); s += __shfl_xor(s, 8);
      if (cid == 0) sRed[wgn][row_local] = s;
    }
  }
  __syncthreads();
  if (tid < 128) atomicAdd(&scores[r0 + tid], sRed[0][tid] + sRed[1][tid]);
}

// ---------------- softmax
__global__ void softmax_k(const float* __restrict__ scores,
                          float* __restrict__ alpha) {
  const int n = blockIdx.x, tid = threadIdx.x;
  __shared__ float red[8];
  float s = (tid < LQ) ? scores[n * LQ + tid] : -1e30f;
  float m = s;
  for (int o = 32; o; o >>= 1) m = fmaxf(m, __shfl_xor(m, o));
  if ((tid & 63) == 0) red[tid >> 6] = m;
  __syncthreads();
  m = fmaxf(fmaxf(red[0], red[1]), fmaxf(red[2], red[3]));
  float e = (tid < LQ) ? __expf(s - m) : 0.f;
  float t = e;
  for (int o = 32; o; o >>= 1) t += __shfl_xor(t, o);
  if ((tid & 63) == 0) red[4 + (tid >> 6)] = t;
  __syncthreads();
  t = red[4] + red[5] + red[6] + red[7];
  if (tid < LQ) alpha[n * LQ + tid] = e / t;
}

// ---------------- wsum reading bf16 copy
__global__ void wsum_bf16_k(const u16* __restrict__ featB,
                            const float* __restrict__ alpha,
                            float* __restrict__ out) {
  const int n = blockIdx.x >> 1, half = blockIdx.x & 1;
  const int tid = threadIdx.x;
  __shared__ float al[LQ];
  if (tid < LQ) al[tid] = alpha[n * LQ + tid];
  __syncthreads();
  const u16* fp = featB + (size_t)n * LQ * DDIM + half * 1024 + tid * 4;
  float ax = 0.f, ay = 0.f, az = 0.f, aw = 0.f;
  #pragma unroll 4
  for (int l = 0; l < LQ; l++) {
    float a = al[l];
    ushort4 u = *(const ushort4*)(fp + (size_t)l * DDIM);
    ax = fmaf(a, bf2f(u.x), ax);
    ay = fmaf(a, bf2f(u.y), ay);
    az = fmaf(a, bf2f(u.z), az);
    aw = fmaf(a, bf2f(u.w), aw);
  }
  float4 r = {ax, ay, az, aw};
  *(float4*)(out + n * DDIM + half * 1024 + tid * 4) = r;
}

// ================= R2 fallback path (ws too small) =================
__global__ void prepB_slow_k(const float* __restrict__ W_enc, u16* __restrict__ Bst) {
  const int ks = blockIdx.x;
  const int tid = threadIdx.x;
  __shared__ u16 ldsT[32 * 520];
  for (int i4 = tid; i4 < 4096; i4 += 256) {
    int dl = i4 >> 7;
    int nn = (i4 & 127) << 2;
    float4 f = *(const float4*)(W_enc + (size_t)(ks * 32 + dl) * 512 + nn);
    *(ushort4*)(&ldsT[dl * 520 + nn]) = cvt4(f);
  }
  __syncthreads();
  for (int idx = tid; idx < 16384; idx += 256) {
    int kq = idx >> 12;
    int n  = (idx >> 3) & 511;
    int e  = idx & 7;
    Bst[(size_t)ks * 16384 + idx] = ldsT[(kq * 8 + e) * 520 + n];
  }
}

__global__ __launch_bounds__(256, 3) void score_gemm_slow_k(
    const float* __restrict__ feature, const u16* __restrict__ Bst,
    const float* __restrict__ att2, const float* __restrict__ W_tot,
    float* __restrict__ scores) {
  __shared__ __align__(16) u16 sA[2][4 * KQP];
  __shared__ __align__(16) u16 sB[2][4 * KQP];
  __shared__ float sRed[2][128];
  const int tid = threadIdx.x;
  const int b = blockIdx.x;
  const int mt = (b >> 5) * 8 + (b & 7);
  const int nt = (b >> 3) & 3;
  const int r0 = mt << 7, n0 = nt << 7;
  const int wid = tid >> 6, lane = tid & 63;
  const int wgm = wid >> 1, wgn = wid & 1;
  const int quad = lane >> 4, cid = lane & 15;
  const int arow = tid >> 3, akk4 = tid & 7;
  const float* gA = feature + (size_t)(r0 + arow) * 2048 + akk4 * 4;
  const int wAoff = (akk4 >> 1) * KQP + (arow << 3) + ((akk4 & 1) << 2);
  const u16* gBlane = Bst + (size_t)wid * 4096 + ((size_t)n0 << 3) + lane * 8;
  const int abase = quad * KQP + (((wgm << 6) + cid) << 3);
  const int bbase = quad * KQP + (((wgn << 6) + cid) << 3);
  f32x4 zero = {0.f, 0.f, 0.f, 0.f};
  f32x4 acc[4][4];
  #pragma unroll
  for (int i = 0; i < 4; i++)
    #pragma unroll
    for (int j = 0; j < 4; j++) acc[i][j] = zero;
  float4 a0, a1, a2, a3;
  {
    const float* p = gA;
    a0 = *(const float4*)(p);
    a1 = *(const float4*)(p + 32 * 2048);
    a2 = *(const float4*)(p + 64 * 2048);
    a3 = *(const float4*)(p + 96 * 2048);
    u16* dst = &sB[0][wid * KQP];
    glds16(gBlane, dst);
    glds16(gBlane + 512, dst + 512);
  }
  for (int ks = 0; ks < 64; ks++) {
    const int buf = ks & 1;
    u16* wa = &sA[buf][wAoff];
    *(ushort4*)(wa)       = cvt4(a0);
    *(ushort4*)(wa + 256) = cvt4(a1);
    *(ushort4*)(wa + 512) = cvt4(a2);
    *(ushort4*)(wa + 768) = cvt4(a3);
    __syncthreads();
    if (ks < 63) {
      const float* p = gA + (ks + 1) * 32;
      a0 = *(const float4*)(p);
      a1 = *(const float4*)(p + 32 * 2048);
      a2 = *(const float4*)(p + 64 * 2048);
      a3 = *(const float4*)(p + 96 * 2048);
      const u16* src = gBlane + (size_t)(ks + 1) * 16384;
      u16* dst = &sB[buf ^ 1][wid * KQP];
      glds16(src, dst);
      glds16(src + 512, dst + 512);
    }
    const u16* sa = &sA[buf][abase];
    const u16* sb = &sB[buf][bbase];
    short8 af[4], bfr[4];
    #pragma unroll
    for (int mi = 0; mi < 4; mi++)
      af[mi] = *(const short8*)(sa + (mi << 7));
    #pragma unroll
    for (int ni = 0; ni < 4; ni++)
      bfr[ni] = *(const short8*)(sb + (ni << 7));
    #pragma unroll
    for (int mi = 0; mi < 4; mi++)
      #pragma unroll
      for (int ni = 0; ni < 4; ni++)
        acc[mi][ni] = __builtin_amdgcn_mfma_f32_16x16x32_bf16(
            af[mi], bfr[ni], acc[mi][ni], 0, 0, 0);
  }
  float wt[4];
  #pragma unroll
  for (int ni = 0; ni < 4; ni++)
    wt[ni] = W_tot[n0 + (wgn << 6) + ni * 16 + cid];
  #pragma unroll
  for (int mi = 0; mi < 4; mi++) {
    #pragma unroll
    for (int reg = 0; reg < 4; reg++) {
      int row_local = (wgm << 6) + mi * 16 + quad * 4 + reg;
      int row_flat = r0 + row_local;
      int nb = row_flat / 196;
      const float* a2r = att2 + nb * 512 + n0 + (wgn << 6);
      float s = 0.f;
      #pragma unroll
      for (int ni = 0; ni < 4; ni++) {
        float v = acc[mi][ni][reg] + a2r[ni * 16 + cid];
        s += fmaxf(v, 0.f) * wt[ni];
      }
      s += __shfl_xor(s, 1); s += __shfl_xor(s, 2);
      s += __shfl_xor(s, 4); s += __shfl_xor(s, 8);
      if (cid == 0) sRed[wgn][row_local] = s;
    }
  }
  __syncthreads();
  if (tid < 128) atomicAdd(&scores[r0 + tid], sRed[0][tid] + sRed[1][tid]);
}

__global__ void wsum_f32_k(const float* __restrict__ feature,
                           const float* __restrict__ alpha,
                           float* __restrict__ out) {
  const int n = blockIdx.x >> 1, half = blockIdx.x & 1;
  const int tid = threadIdx.x;
  __shared__ float al[LQ];
  if (tid < LQ) al[tid] = alpha[n * LQ + tid];
  __syncthreads();
  const float* fp = feature + (size_t)n * LQ * DDIM + half * 1024 + tid * 4;
  float4 acc = {0.f, 0.f, 0.f, 0.f};
  #pragma unroll 4
  for (int l = 0; l < LQ; l++) {
    float a = al[l];
    float4 f = *(const float4*)(fp + (size_t)l * DDIM);
    acc.x = fmaf(a, f.x, acc.x); acc.y = fmaf(a, f.y, acc.y);
    acc.z = fmaf(a, f.z, acc.z); acc.w = fmaf(a, f.w, acc.w);
  }
  *(float4*)(out + n * DDIM + half * 1024 + tid * 4) = acc;
}

extern "C" void kernel_launch(void* const* d_in, const int* in_sizes, int n_in,
                              void* d_out, int out_size, void* d_ws, size_t ws_size,
                              hipStream_t stream) {
  const float* feature = (const float*)d_in[0];
  const float* prev_h  = (const float*)d_in[1];
  const float* W_enc   = (const float*)d_in[2];
  const float* b_enc   = (const float*)d_in[3];
  const float* W_dec   = (const float*)d_in[4];
  const float* b_dec   = (const float*)d_in[5];
  const float* W_tot   = (const float*)d_in[6];
  // d_in[7] = b_tot: softmax-invariant, unused

  float* out   = (float*)d_out;
  float* wf    = out;
  float* alpha = out + WF_N;

  char* ws = (char*)d_ws;
  const size_t featB_bytes = (size_t)MTOT * DDIM * 2;   // 205,520,896
  const size_t need = featB_bytes + (2u << 20) + (512u << 10) + (256u << 10);

  if (ws_size >= need) {
    u16*   featB  = (u16*)ws;
    u16*   WencT  = (u16*)(ws + featB_bytes);
    float* att2   = (float*)(ws + featB_bytes + (2u << 20));
    float* scores = (float*)(ws + featB_bytes + (2u << 20) + (512u << 10));

    cvtA_k<<<12544, 256, 0, stream>>>(feature, featB);
    prepBT_k<<<256, 256, 0, stream>>>(W_enc, WencT);
    att2_k<<<256, 256, 0, stream>>>(prev_h, W_dec, b_dec, b_enc, att2);
    zero_scores_k<<<196, 256, 0, stream>>>(scores);
    score_gemm_k<<<1568, 256, 0, stream>>>(featB, WencT, att2, W_tot, scores);
    softmax_k<<<256, 256, 0, stream>>>(scores, alpha);
    wsum_bf16_k<<<512, 256, 0, stream>>>(featB, alpha, wf);
  } else {
    u16*   Bst    = (u16*)ws;
    float* att2   = (float*)(ws + (2u << 20));
    float* scores = (float*)(ws + (2u << 20) + (512u << 10));

    prepB_slow_k<<<64, 256, 0, stream>>>(W_enc, Bst);
    att2_k<<<256, 256, 0, stream>>>(prev_h, W_dec, b_dec, b_enc, att2);
    zero_scores_k<<<196, 256, 0, stream>>>(scores);
    score_gemm_slow_k<<<1568, 256, 0, stream>>>(feature, Bst, att2, W_tot, scores);
    softmax_k<<<256, 256, 0, stream>>>(scores, alpha);
    wsum_f32_k<<<512, 256, 0, stream>>>(feature, alpha, wf);
  }
}